// Round 8
// baseline (157.805 us; speedup 1.0000x reference)
//
#include <hip/hip_runtime.h>

#define N_ELEM 4096
#define BLOCK 256
#define PER 16             // elems per thread per row
#define NG (PER / 2)       // v2f groups per thread per row = 8
#define NWAVE (BLOCK / 64) // 4
#define ROWS 4             // R17: four rows per block (w shared by 4 rows)
#define CAPACITY 600.0f
#define DAMPING 1e-3f
// R16 post-mortem (the key finding): R15 (cap 18) vs R16 (cap 13) were
// time-identical with bit-identical absmax => the |dlam|<1e-5 gate FIRES
// at it~9-11 in both. "Never fires" (R13 claim) was wrong; all of
// R13/R15/R16 ran ~11 evals. Schedule is near-minimal; remaining cost is
// per-eval issue + serial reduce tails (ds_bpermute butterfly ~6x30cy
// dependent + barrier + stage2, only 2 blocks/CU to hide it) and the
// 2-round grid (1024 blocks, 2 resident/CU -> load ramp paid twice).
// R17 (semantics byte-identical; only summation tree + row packing):
//  - ROWS=4: grid 512 -> single residency round; w/w^2 shared by 4 rows;
//    ONE barrier+stage2+scalar section serves 4 rows (overhead /2 vs R16)
//  - DPP wave reduction (row_shr 1/2/4/8 + row_bcast15/31 adds): VALU
//    pipe, ~4cy/step dependent latency, replaces 6 dependent ds_bpermute
//    rounds per value (8 values would have doubled LDS-pipe traffic)
// Schedule/gate unchanged: 3 warmup (mu=1) + 4 ladder (x1/4) + final-mu
// Newtons; gate |dl|<1e-5 (all 4 rows) at it>=9; cap 13; break WITHOUT
// applying dlam; emit = KKT refine at (lam, dlam).
#define NITER 13
#define N_MU1 3
#define FIRST_FINAL 7      // first it with mu = DAMPING
#define GATE_IT 9
#define GATE_EPS 1e-5f

typedef float v2f __attribute__((ext_vector_type(2)));
union F4V2 { float4 f4; v2f v[2]; };

__device__ __forceinline__ float raw_rcp(float a)  { return __builtin_amdgcn_rcpf(a); }
__device__ __forceinline__ float raw_sqrt(float a) { return __builtin_amdgcn_sqrtf(a); }
__device__ __forceinline__ v2f pk_rcp(v2f a) {
    v2f r; r.x = raw_rcp(a.x); r.y = raw_rcp(a.y); return r;
}
__device__ __forceinline__ v2f pk_sqrt(v2f a) {
    v2f r; r.x = raw_sqrt(a.x); r.y = raw_sqrt(a.y); return r;
}
__device__ __forceinline__ v2f pk_copysign(v2f m, v2f s) {
    v2f r; r.x = __builtin_copysignf(m.x, s.x); r.y = __builtin_copysignf(m.y, s.y);
    return r;
}
__device__ __forceinline__ float bcast_first(float v) {
    return __uint_as_float(__builtin_amdgcn_readfirstlane(__float_as_uint(v)));
}

// R17: DPP-based wave sum (gfx9 pattern, rocPRIM-style). All-VALU, no LDS.
// After the 6 steps, lane 63 holds the wave total. old=0 + bound_ctrl=false
// => masked/invalid lanes contribute 0 to the adds.
template <int CTRL, int RMASK>
__device__ __forceinline__ float dpp_add(float v) {
    const int m = __builtin_amdgcn_update_dpp(
        0, __float_as_int(v), CTRL, RMASK, 0xF, false);
    return v + __int_as_float(m);
}
__device__ __forceinline__ float wave_sum63(float v) {
    v = dpp_add<0x111, 0xF>(v);   // row_shr:1
    v = dpp_add<0x112, 0xF>(v);   // row_shr:2
    v = dpp_add<0x114, 0xF>(v);   // row_shr:4
    v = dpp_add<0x118, 0xF>(v);   // row_shr:8  -> lane15/31/47/63 = row sums
    v = dpp_add<0x142, 0xA>(v);   // row_bcast:15 (rows 1,3): lane31=sum0-31, 63=sum32-63
    v = dpp_add<0x143, 0xC>(v);   // row_bcast:31 (rows 2,3): lane63 = total
    return v;
}

// Layout: w + 4 rows of c in registers/AGPRs; NO per-element state across
// iterations. Per eval: pure-VALU pass (4 rows interleaved, deep ILP),
// DPP reduce (8 sums), ONE barrier, 4 scalar Newtons. LDS = 256 B.
__global__ __launch_bounds__(BLOCK, 4) void ipm_knapsack_kernel(
        const float* __restrict__ costs,
        const float* __restrict__ weights,
        float* __restrict__ out) {
    __shared__ float4 ldsA[2][NWAVE];     // s0 of rows 0..3 (parity-buffered)
    __shared__ float4 ldsB[2][NWAVE];     // s2 of rows 0..3
    const int row0 = ROWS * blockIdx.x;
    const int t    = threadIdx.x;

    v2f w[NG], c[ROWS][NG];

    // ---- Load w and 4 rows' c (negated) into registers ----
    const float4* wg = reinterpret_cast<const float4*>(weights);
    #pragma unroll
    for (int j = 0; j < NG / 2; ++j) {
        F4V2 ww;
        ww.f4 = wg[t + BLOCK * j];
        w[2 * j] = ww.v[0]; w[2 * j + 1] = ww.v[1];
        #pragma unroll
        for (int rr = 0; rr < ROWS; ++rr) {
            const float4* cg =
                reinterpret_cast<const float4*>(costs + (size_t)(row0 + rr) * N_ELEM);
            F4V2 cc;
            cc.f4 = cg[t + BLOCK * j];
            cc.f4.x = -cc.f4.x; cc.f4.y = -cc.f4.y;
            cc.f4.z = -cc.f4.z; cc.f4.w = -cc.f4.w;
            c[rr][2 * j] = cc.v[0]; c[rr][2 * j + 1] = cc.v[1];
        }
    }

    float lam[ROWS], dl[ROWS];
    #pragma unroll
    for (int rr = 0; rr < ROWS; ++rr) { lam[rr] = 0.0f; dl[rr] = 0.0f; }

    // Per-element core (UNCHANGED from R15/R16 — verified). Quadratic
    // r x^2 - (r+2mu) x + mu = 0; D = r^2+4mu^2 exact; den = |r|+2mu+sqrt(D)
    // (no cancellation); x' = 2mu/den; x = 0.5 - copysign(0.5-x', r);
    // AB2 = H*mu = D + 2mu*s (verified identity); rq = rcp(den*AB2) serves
    // both 1/den (rq*AB2, AB2 cancels exactly in x') and 1/AB2 (rq*den).
    #define ELEM_CORE(r_, wk_, wsq_, s0_, s2_)                                 \
        {                                                                      \
            const v2f a_   = __builtin_elementwise_abs(r_);                    \
            const v2f D_   = r_ * r_ + mu4sq;                                  \
            const v2f s_   = pk_sqrt(D_);                                      \
            const v2f den_ = (a_ + two_mu) + s_;                               \
            const v2f AB2_ = two_mu * s_ + D_;                                 \
            const v2f rq_  = pk_rcp(den_ * AB2_);                              \
            const v2f xp_  = two_mu * (rq_ * AB2_);                            \
            const v2f xk_  = 0.5f - pk_copysign(0.5f - xp_, r_);               \
            s0_ = wk_ * xk_ + s0_;                                             \
            s2_ = wsq_ * (rq_ * den_) + s2_;                                   \
        }

    for (int it = 0; it < NITER; ++it) {
        // mu: 1,1,1, .25, .0625, .015625, .00390625, then DAMPING forever.
        const float mu = (it < N_MU1) ? 1.0f
                       : (it < FIRST_FINAL)
                         ? __uint_as_float((unsigned)(127 - 2 * (it - (N_MU1 - 1))) << 23)
                         : DAMPING;
        const float two_mu = 2.0f * mu;
        const float mu4sq  = 4.0f * mu * mu;

        v2f s0[ROWS], s2[ROWS];
        #pragma unroll
        for (int rr = 0; rr < ROWS; ++rr) {
            v2f z = {0.0f, 0.0f}; s0[rr] = z; s2[rr] = z;
        }
        #pragma unroll
        for (int k = 0; k < NG; ++k) {
            const v2f wk  = w[k];
            const v2f wsq = wk * wk;
            #pragma unroll
            for (int rr = 0; rr < ROWS; ++rr) {
                const v2f r_ = lam[rr] * wk + c[rr][k];
                ELEM_CORE(r_, wk, wsq, s0[rr], s2[rr]);
            }
        }

        // ---- 8-value reduce: DPP wave sums -> lane63 writes -> stage 2 ----
        float a0 = wave_sum63(s0[0].x + s0[0].y);
        float a1 = wave_sum63(s0[1].x + s0[1].y);
        float a2 = wave_sum63(s0[2].x + s0[2].y);
        float a3 = wave_sum63(s0[3].x + s0[3].y);
        float b0 = wave_sum63(s2[0].x + s2[0].y);
        float b1 = wave_sum63(s2[1].x + s2[1].y);
        float b2 = wave_sum63(s2[2].x + s2[2].y);
        float b3 = wave_sum63(s2[3].x + s2[3].y);
        const int par  = it & 1;
        const int wave = t >> 6;
        if ((t & 63) == 63) {
            float4 pa = {a0, a1, a2, a3}; ldsA[par][wave] = pa;
            float4 pb = {b0, b1, b2, b3}; ldsB[par][wave] = pb;
        }
        __syncthreads();
        float4 pA = ldsA[par][0], pB = ldsB[par][0];
        #pragma unroll
        for (int i = 1; i < NWAVE; ++i) {
            float4 qa = ldsA[par][i], qb = ldsB[par][i];
            pA.x += qa.x; pA.y += qa.y; pA.z += qa.z; pA.w += qa.w;
            pB.x += qb.x; pB.y += qb.y; pB.z += qb.z; pB.w += qb.w;
        }
        // Schur: dl = (sum(w*x) - cap) / (mu * sum(w^2/AB2))
        dl[0] = bcast_first((pA.x - CAPACITY) * raw_rcp(mu * pB.x));
        dl[1] = bcast_first((pA.y - CAPACITY) * raw_rcp(mu * pB.y));
        dl[2] = bcast_first((pA.z - CAPACITY) * raw_rcp(mu * pB.z));
        dl[3] = bcast_first((pA.w - CAPACITY) * raw_rcp(mu * pB.w));

        const float gm = fmaxf(fmaxf(fabsf(dl[0]), fabsf(dl[1])),
                               fmaxf(fabsf(dl[2]), fabsf(dl[3])));
        // Break WITHOUT applying dlam: (lam, dlam) pair feeds the emit
        // refine. Gate fires ~it 9-11 (R16-proven). Uniform branch.
        if ((it >= GATE_IT && gm < GATE_EPS) || it == NITER - 1) break;
        #pragma unroll
        for (int rr = 0; rr < ROWS; ++rr) lam[rr] += dl[rr];
    }
    #undef ELEM_CORE

    // ---- Emit pass: recompute x, w/H at (lam, mu=DAMPING); refine:
    // out = x - dlam * w/H  (== reference _kkt_refine with F1 == 0).
    {
        const float mu = DAMPING;
        const float two_mu = 2.0f * mu;
        const float mu4sq  = 4.0f * mu * mu;
        #pragma unroll
        for (int j = 0; j < NG / 2; ++j) {
            #pragma unroll
            for (int rr = 0; rr < ROWS; ++rr) {
                float4* og =
                    reinterpret_cast<float4*>(out + (size_t)(row0 + rr) * N_ELEM);
                F4V2 ov;
                #pragma unroll
                for (int h = 0; h < 2; ++h) {
                    const int k = 2 * j + h;
                    const v2f wk   = w[k];
                    const v2f r_   = lam[rr] * wk + c[rr][k];
                    const v2f a_   = __builtin_elementwise_abs(r_);
                    const v2f D_   = r_ * r_ + mu4sq;
                    const v2f s_   = pk_sqrt(D_);
                    const v2f den_ = (a_ + two_mu) + s_;
                    const v2f AB2_ = two_mu * s_ + D_;
                    const v2f rq_  = pk_rcp(den_ * AB2_);
                    const v2f xp_  = two_mu * (rq_ * AB2_);
                    const v2f xk_  = 0.5f - pk_copysign(0.5f - xp_, r_);
                    const v2f wi_  = (mu * wk) * (rq_ * den_);
                    ov.v[h] = xk_ - dl[rr] * wi_;
                }
                og[t + BLOCK * j] = ov.f4;
            }
        }
    }
}

extern "C" void kernel_launch(void* const* d_in, const int* in_sizes, int n_in,
                              void* d_out, int out_size, void* d_ws, size_t ws_size,
                              hipStream_t stream) {
    const float* costs   = (const float*)d_in[0];
    const float* weights = (const float*)d_in[1];
    float* out = (float*)d_out;
    const int B = in_sizes[0] / N_ELEM;   // 2048 rows
    ipm_knapsack_kernel<<<B / ROWS, BLOCK, 0, stream>>>(costs, weights, out);
}

// Round 9
// 115.814 us; speedup vs baseline: 1.3626x; 1.3626x over previous
//
#include <hip/hip_runtime.h>

#define N_ELEM 4096
#define BLOCK 64           // R18: ONE WAVE per block -> no barrier, no LDS
#define PER 64             // elems per thread (one row per wave)
#define NG (PER / 2)       // 32 v2f groups
#define CAPACITY 600.0f
#define DAMPING 1e-3f
// R17 post-mortem: ROWS=4 spilled (WRITE 32->62MB, FETCH 16->37MB = scratch
// round-trip; VALUBusy 39%, 94us). launch_bounds(256,4) caps 128 VGPR but
// ROWS=4 needs ~120-140 -> allocator spilled c[][] to scratch. The DPP
// wave reduce itself is HW-verified (R17 passed, absmax bit-identical).
// R18: keep R16 semantics EXACTLY (ELEM_CORE, mu ladder, gate, emit), but
// restructure to 1 wave = 1 row: BLOCK=64, PER=64, c+w in regs (~128 data
// + ~40 temps < 256 cap from launch_bounds(64,2); NO spill). Per-eval
// overhead drops from {2x6 dependent ds_swizzle rounds + LDS + s_barrier +
// stage2 + bcast, ~500-600cy exposed at 2 blk/CU} to {6 DPP VALU adds
// (~4cy each) + readlane, ~60cy}. Grid 2048 single-wave blocks = 8
// waves/CU exactly, one residency round. Total VALU issue work unchanged;
// only the serial tail shrinks.
// Schedule (R16-proven): 3 warmup (mu=1) + 4 ladder (x1/4 to 0.0039) +
// final-mu Newtons; gate |dl|<1e-5 at it>=9 (fires ~it 9-11); cap 13;
// break WITHOUT applying dlam; emit = KKT refine at (lam, dlam).
#define NITER 13
#define N_MU1 3
#define FIRST_FINAL 7      // first it with mu = DAMPING
#define GATE_IT 9
#define GATE_EPS 1e-5f

typedef float v2f __attribute__((ext_vector_type(2)));
union F4V2 { float4 f4; v2f v[2]; };

__device__ __forceinline__ float raw_rcp(float a)  { return __builtin_amdgcn_rcpf(a); }
__device__ __forceinline__ float raw_sqrt(float a) { return __builtin_amdgcn_sqrtf(a); }
__device__ __forceinline__ v2f pk_rcp(v2f a) {
    v2f r; r.x = raw_rcp(a.x); r.y = raw_rcp(a.y); return r;
}
__device__ __forceinline__ v2f pk_sqrt(v2f a) {
    v2f r; r.x = raw_sqrt(a.x); r.y = raw_sqrt(a.y); return r;
}
__device__ __forceinline__ v2f pk_copysign(v2f m, v2f s) {
    v2f r; r.x = __builtin_copysignf(m.x, s.x); r.y = __builtin_copysignf(m.y, s.y);
    return r;
}

// DPP-based wave64 sum (HW-verified in R17). All-VALU, no LDS. After the 6
// steps lane 63 holds the wave total; masked rows add old=0 (no-op).
template <int CTRL, int RMASK>
__device__ __forceinline__ float dpp_add(float v) {
    const int m = __builtin_amdgcn_update_dpp(
        0, __float_as_int(v), CTRL, RMASK, 0xF, false);
    return v + __int_as_float(m);
}
__device__ __forceinline__ float wave_sum63(float v) {
    v = dpp_add<0x111, 0xF>(v);   // row_shr:1
    v = dpp_add<0x112, 0xF>(v);   // row_shr:2
    v = dpp_add<0x114, 0xF>(v);   // row_shr:4
    v = dpp_add<0x118, 0xF>(v);   // row_shr:8  -> lane15/31/47/63 = row sums
    v = dpp_add<0x142, 0xA>(v);   // row_bcast:15 -> lane31, lane63 accumulate
    v = dpp_add<0x143, 0xC>(v);   // row_bcast:31 -> lane63 = wave total
    return v;
}
__device__ __forceinline__ float lane63(float v) {
    return __uint_as_float(__builtin_amdgcn_readlane(__float_as_uint(v), 63));
}

// Layout: c (64) + w (64) floats in arch VGPRs + ~40 temps, cap 256 via
// launch_bounds(64,2) -> no spill (R17 lesson). No per-element state across
// iterations; emit recomputes x, w/H once at (lam, dlam).
__global__ __launch_bounds__(BLOCK, 2) void ipm_knapsack_kernel(
        const float* __restrict__ costs,
        const float* __restrict__ weights,
        float* __restrict__ out) {
    const int row = blockIdx.x;
    const int t   = threadIdx.x;

    v2f w[NG], c[NG];

    // ---- Load w and this row's c (negated) into registers ----
    const float4* wg = reinterpret_cast<const float4*>(weights);
    const float4* cg = reinterpret_cast<const float4*>(costs + (size_t)row * N_ELEM);
    #pragma unroll
    for (int j = 0; j < NG / 2; ++j) {
        F4V2 ww, cc;
        ww.f4 = wg[t + BLOCK * j];
        cc.f4 = cg[t + BLOCK * j];
        cc.f4.x = -cc.f4.x; cc.f4.y = -cc.f4.y; cc.f4.z = -cc.f4.z; cc.f4.w = -cc.f4.w;
        w[2 * j] = ww.v[0]; w[2 * j + 1] = ww.v[1];
        c[2 * j] = cc.v[0]; c[2 * j + 1] = cc.v[1];
    }

    float lam = 0.0f, dl = 0.0f;

    // Per-element core (UNCHANGED from R15/R16 — verified). Quadratic
    // r x^2 - (r+2mu) x + mu = 0; D = r^2+4mu^2 exact; den = |r|+2mu+sqrt(D)
    // (no cancellation); x' = 2mu/den; x = 0.5 - copysign(0.5-x', r);
    // AB2 = H*mu = D + 2mu*s (verified identity); rq = rcp(den*AB2) serves
    // both 1/den (rq*AB2, AB2 cancels exactly in x') and 1/AB2 (rq*den).
    #define ELEM_CORE(r_, wk_, wsq_, s0_, s2_)                                 \
        {                                                                      \
            const v2f a_   = __builtin_elementwise_abs(r_);                    \
            const v2f D_   = r_ * r_ + mu4sq;                                  \
            const v2f s_   = pk_sqrt(D_);                                      \
            const v2f den_ = (a_ + two_mu) + s_;                               \
            const v2f AB2_ = two_mu * s_ + D_;                                 \
            const v2f rq_  = pk_rcp(den_ * AB2_);                              \
            const v2f xp_  = two_mu * (rq_ * AB2_);                            \
            const v2f xk_  = 0.5f - pk_copysign(0.5f - xp_, r_);               \
            s0_ = wk_ * xk_ + s0_;                                             \
            s2_ = wsq_ * (rq_ * den_) + s2_;                                   \
        }

    for (int it = 0; it < NITER; ++it) {
        // mu: 1,1,1, .25, .0625, .015625, .00390625, then DAMPING forever.
        const float mu = (it < N_MU1) ? 1.0f
                       : (it < FIRST_FINAL)
                         ? __uint_as_float((unsigned)(127 - 2 * (it - (N_MU1 - 1))) << 23)
                         : DAMPING;
        const float two_mu = 2.0f * mu;
        const float mu4sq  = 4.0f * mu * mu;

        v2f s0 = {0.0f, 0.0f}, s2 = {0.0f, 0.0f};
        #pragma unroll
        for (int k = 0; k < NG; ++k) {
            const v2f wk  = w[k];
            const v2f wsq = wk * wk;
            const v2f r_  = lam * wk + c[k];
            ELEM_CORE(r_, wk, wsq, s0, s2);
        }

        // ---- Wave-only reduce: 6 DPP adds per value, then readlane 63 ----
        const float s0t = lane63(wave_sum63(s0.x + s0.y));
        const float s2t = lane63(wave_sum63(s2.x + s2.y));
        // Schur: dl = (sum(w*x) - cap) / (mu * sum(w^2/AB2))
        dl = (s0t - CAPACITY) * raw_rcp(mu * s2t);

        // Break WITHOUT applying dlam: (lam, dlam) feeds the emit refine.
        // Gate fires ~it 9-11 (R16-proven). Uniform branch (readlane SGPR).
        if ((it >= GATE_IT && fabsf(dl) < GATE_EPS) || it == NITER - 1) break;
        lam += dl;
    }
    #undef ELEM_CORE

    // ---- Emit pass: recompute x, w/H at (lam, mu=DAMPING); refine:
    // out = x - dlam * w/H  (== reference _kkt_refine with F1 == 0).
    {
        const float mu = DAMPING;
        const float two_mu = 2.0f * mu;
        const float mu4sq  = 4.0f * mu * mu;
        float4* og = reinterpret_cast<float4*>(out + (size_t)row * N_ELEM);
        #pragma unroll
        for (int j = 0; j < NG / 2; ++j) {
            F4V2 ov;
            #pragma unroll
            for (int h = 0; h < 2; ++h) {
                const int k = 2 * j + h;
                const v2f wk   = w[k];
                const v2f r_   = lam * wk + c[k];
                const v2f a_   = __builtin_elementwise_abs(r_);
                const v2f D_   = r_ * r_ + mu4sq;
                const v2f s_   = pk_sqrt(D_);
                const v2f den_ = (a_ + two_mu) + s_;
                const v2f AB2_ = two_mu * s_ + D_;
                const v2f rq_  = pk_rcp(den_ * AB2_);
                const v2f xp_  = two_mu * (rq_ * AB2_);
                const v2f xk_  = 0.5f - pk_copysign(0.5f - xp_, r_);
                const v2f wi_  = (mu * wk) * (rq_ * den_);
                ov.v[h] = xk_ - dl * wi_;
            }
            og[t + BLOCK * j] = ov.f4;
        }
    }
}

extern "C" void kernel_launch(void* const* d_in, const int* in_sizes, int n_in,
                              void* d_out, int out_size, void* d_ws, size_t ws_size,
                              hipStream_t stream) {
    const float* costs   = (const float*)d_in[0];
    const float* weights = (const float*)d_in[1];
    float* out = (float*)d_out;
    const int B = in_sizes[0] / N_ELEM;   // 2048 rows -> 2048 single-wave blocks
    ipm_knapsack_kernel<<<B, BLOCK, 0, stream>>>(costs, weights, out);
}